// Round 1
// baseline (193.459 us; speedup 1.0000x reference)
//
#include <hip/hip_runtime.h>
#include <math.h>

// Problem constants (from reference setup_inputs)
constexpr int NB = 16;          // batches
constexpr int XY = 512 * 512;   // pixels per image
constexpr int NV = XY / 4;      // float4 vectors per image
constexpr int WS_STRIDE = 32;   // doubles per batch in workspace

// Workspace layout per batch (doubles), offset b*WS_STRIDE:
//  [0]        : mask count  (Σ mask)
//  [1..4]     : S0[k]  = Σ w_k                (w_k = pred_k * mask)
//  [5..16]    : S1[k*3+m] = Σ w_k * inp_m
//  [17..28]   : S2[k*3+m] = Σ w_k * inp_m^2
//  [29]       : Σ loglik * mask

__device__ __forceinline__ float waveReduce64(float v) {
#pragma unroll
    for (int off = 32; off > 0; off >>= 1) v += __shfl_down(v, off, 64);
    return v;
}

__global__ __launch_bounds__(256) void pass1_moments(
        const float* __restrict__ predictions,
        const float* __restrict__ inputs,
        const int*   __restrict__ heart,
        double*      __restrict__ ws) {
    const int b = blockIdx.y;
    const float4* q0 = reinterpret_cast<const float4*>(predictions + (size_t)b * 5 * XY + 1 * XY);
    const float4* q1 = reinterpret_cast<const float4*>(predictions + (size_t)b * 5 * XY + 2 * XY);
    const float4* q2 = reinterpret_cast<const float4*>(predictions + (size_t)b * 5 * XY + 3 * XY);
    const float4* q3 = reinterpret_cast<const float4*>(predictions + (size_t)b * 5 * XY + 4 * XY);
    const float4* i0 = reinterpret_cast<const float4*>(inputs + (size_t)b * 3 * XY + 0 * XY);
    const float4* i1 = reinterpret_cast<const float4*>(inputs + (size_t)b * 3 * XY + 1 * XY);
    const float4* i2 = reinterpret_cast<const float4*>(inputs + (size_t)b * 3 * XY + 2 * XY);
    const int4*   hh = reinterpret_cast<const int4*>(heart + (size_t)b * XY);

    float acc[29];
#pragma unroll
    for (int i = 0; i < 29; i++) acc[i] = 0.f;

    const int tid0   = blockIdx.x * blockDim.x + threadIdx.x;
    const int stride = gridDim.x * blockDim.x;

    for (int v = tid0; v < NV; v += stride) {
        int4   h  = hh[v];
        float4 a0 = i0[v], a1 = i1[v], a2 = i2[v];
        float4 p0 = q0[v], p1 = q1[v], p2 = q2[v], p3 = q3[v];

        auto proc = [&](int hv, float e0, float e1, float e2,
                        float w0, float w1, float w2, float w3) {
            const float m = (hv == 1) ? 1.f : 0.f;
            acc[0] += m;
            float inv[3] = {e0, e1, e2};
            float wk[4]  = {w0 * m, w1 * m, w2 * m, w3 * m};
#pragma unroll
            for (int k = 0; k < 4; k++) {
                acc[1 + k] += wk[k];
#pragma unroll
                for (int mm = 0; mm < 3; mm++) {
                    float wi = wk[k] * inv[mm];
                    acc[5 + k * 3 + mm]  += wi;
                    acc[17 + k * 3 + mm] += wi * inv[mm];
                }
            }
        };
        proc(h.x, a0.x, a1.x, a2.x, p0.x, p1.x, p2.x, p3.x);
        proc(h.y, a0.y, a1.y, a2.y, p0.y, p1.y, p2.y, p3.y);
        proc(h.z, a0.z, a1.z, a2.z, p0.z, p1.z, p2.z, p3.z);
        proc(h.w, a0.w, a1.w, a2.w, p0.w, p1.w, p2.w, p3.w);
    }

    // block reduce 29 scalars: wave shuffle, then LDS across 4 waves
    __shared__ float sh[4][29];
    const int lane = threadIdx.x & 63;
    const int wav  = threadIdx.x >> 6;
#pragma unroll
    for (int i = 0; i < 29; i++) {
        float v = waveReduce64(acc[i]);
        if (lane == 0) sh[wav][i] = v;
    }
    __syncthreads();
    if (threadIdx.x < 29) {
        float v = sh[0][threadIdx.x] + sh[1][threadIdx.x] + sh[2][threadIdx.x] + sh[3][threadIdx.x];
        atomicAdd(&ws[(size_t)b * WS_STRIDE + threadIdx.x], (double)v);
    }
}

__global__ __launch_bounds__(256) void pass2_loglik(
        const float* __restrict__ predictions,
        const float* __restrict__ inputs,
        const int*   __restrict__ heart,
        double*      __restrict__ ws) {
    const int b = blockIdx.y;
    const double* w = ws + (size_t)b * WS_STRIDE;

    // Reconstruct mu, 1/(2var), and C_k = prod_m 1/sqrt(2*pi*var) in f64 (uniform per block)
    float mu[4][3], hiv[4][3], Ck[4];
#pragma unroll
    for (int k = 0; k < 4; k++) {
        double S0    = w[1 + k];
        double denom = S0 + 1e-10;
        double C     = 1.0;
#pragma unroll
        for (int mm = 0; mm < 3; mm++) {
            double S1  = w[5 + k * 3 + mm];
            double S2  = w[17 + k * 3 + mm];
            double m_  = S1 / denom;
            double var = (S2 - 2.0 * m_ * S1 + m_ * m_ * S0) / denom + 1e-10;
            mu[k][mm]  = (float)m_;
            hiv[k][mm] = (float)(0.5 / var);
            C *= 1.0 / sqrt(6.283185307179586 * var);
        }
        Ck[k] = (float)C;
    }

    const float4* q0 = reinterpret_cast<const float4*>(predictions + (size_t)b * 5 * XY + 1 * XY);
    const float4* q1 = reinterpret_cast<const float4*>(predictions + (size_t)b * 5 * XY + 2 * XY);
    const float4* q2 = reinterpret_cast<const float4*>(predictions + (size_t)b * 5 * XY + 3 * XY);
    const float4* q3 = reinterpret_cast<const float4*>(predictions + (size_t)b * 5 * XY + 4 * XY);
    const float4* i0 = reinterpret_cast<const float4*>(inputs + (size_t)b * 3 * XY + 0 * XY);
    const float4* i1 = reinterpret_cast<const float4*>(inputs + (size_t)b * 3 * XY + 1 * XY);
    const float4* i2 = reinterpret_cast<const float4*>(inputs + (size_t)b * 3 * XY + 2 * XY);
    const int4*   hh = reinterpret_cast<const int4*>(heart + (size_t)b * XY);

    float lacc = 0.f;
    const int tid0   = blockIdx.x * blockDim.x + threadIdx.x;
    const int stride = gridDim.x * blockDim.x;

    for (int v = tid0; v < NV; v += stride) {
        int4   h  = hh[v];
        float4 a0 = i0[v], a1 = i1[v], a2 = i2[v];
        float4 p0 = q0[v], p1 = q1[v], p2 = q2[v], p3 = q3[v];

        auto proc = [&](int hv, float e0, float e1, float e2,
                        float w0, float w1, float w2, float w3) {
            const float m = (hv == 1) ? 1.f : 0.f;
            float pk[4]  = {w0, w1, w2, w3};
            float inv[3] = {e0, e1, e2};
            float mix = 0.f;
#pragma unroll
            for (int k = 0; k < 4; k++) {
                float d0 = inv[0] - mu[k][0];
                float d1 = inv[1] - mu[k][1];
                float d2 = inv[2] - mu[k][2];
                float e  = d0 * d0 * hiv[k][0] + d1 * d1 * hiv[k][1] + d2 * d2 * hiv[k][2];
                float p3c = pk[k] * pk[k] * pk[k];
                mix += Ck[k] * p3c * __expf(-e);
            }
            lacc += m * __logf(mix + 1e-10f);
        };
        proc(h.x, a0.x, a1.x, a2.x, p0.x, p1.x, p2.x, p3.x);
        proc(h.y, a0.y, a1.y, a2.y, p0.y, p1.y, p2.y, p3.y);
        proc(h.z, a0.z, a1.z, a2.z, p0.z, p1.z, p2.z, p3.z);
        proc(h.w, a0.w, a1.w, a2.w, p0.w, p1.w, p2.w, p3.w);
    }

    __shared__ float sh[4];
    const int lane = threadIdx.x & 63;
    const int wav  = threadIdx.x >> 6;
    float v = waveReduce64(lacc);
    if (lane == 0) sh[wav] = v;
    __syncthreads();
    if (threadIdx.x == 0) {
        float t = sh[0] + sh[1] + sh[2] + sh[3];
        atomicAdd(&ws[(size_t)b * WS_STRIDE + 29], (double)t);
    }
}

__global__ void finalize_kernel(const double* __restrict__ ws, float* __restrict__ out) {
    const int lane = threadIdx.x;
    double v = 0.0;
    if (lane < NB) {
        double cnt = ws[(size_t)lane * WS_STRIDE + 0];
        double ll  = ws[(size_t)lane * WS_STRIDE + 29];
        v = -ll / cnt;
    }
#pragma unroll
    for (int off = 8; off > 0; off >>= 1) v += __shfl_down(v, off, 64);
    if (lane == 0) out[0] = (float)(v / (double)NB);
}

extern "C" void kernel_launch(void* const* d_in, const int* in_sizes, int n_in,
                              void* d_out, int out_size, void* d_ws, size_t ws_size,
                              hipStream_t stream) {
    const float* predictions = (const float*)d_in[0];
    const float* inputs      = (const float*)d_in[1];
    const int*   heart       = (const int*)d_in[2];
    float*  out = (float*)d_out;
    double* ws  = (double*)d_ws;

    // zero the accumulator workspace (harness poisons it with 0xAA)
    hipMemsetAsync(d_ws, 0, (size_t)NB * WS_STRIDE * sizeof(double), stream);

    pass1_moments<<<dim3(64, NB), 256, 0, stream>>>(predictions, inputs, heart, ws);
    pass2_loglik <<<dim3(64, NB), 256, 0, stream>>>(predictions, inputs, heart, ws);
    finalize_kernel<<<1, 64, 0, stream>>>(ws, out);
}

// Round 2
// 193.175 us; speedup vs baseline: 1.0015x; 1.0015x over previous
//
#include <hip/hip_runtime.h>
#include <math.h>

// Problem constants (from reference setup_inputs)
constexpr int NB = 16;          // batches
constexpr int XY = 512 * 512;   // pixels per image
constexpr int NV = XY / 4;      // float4 vectors per image
constexpr int WS_STRIDE = 32;   // doubles per batch in workspace

// Workspace layout per batch (doubles), offset b*WS_STRIDE:
//  [0]      : mask count (Σ mask)
//  [1..4]   : S0[k]      = Σ w_k            (w_k = pred_k * mask)
//  [5..16]  : S1[k*3+m]  = Σ w_k * inp_m
//  [17..28] : S2[k*3+m]  = Σ w_k * inp_m^2
//  [29]     : Σ loglik * mask

__device__ __forceinline__ float waveReduce64(float v) {
#pragma unroll
    for (int off = 32; off > 0; off >>= 1) v += __shfl_down(v, off, 64);
    return v;
}

// Straight-line per-pixel moment accumulation. All accumulators are NAMED
// SCALARS — no arrays, no lambdas (the round-1 lambda+array version spilled
// the 29 accumulators to scratch: VGPR=44, VALUBusy 9.6%, 50us even L3-warm).
#define PIX1(h_, e0_, e1_, e2_, p0_, p1_, p2_, p3_) do {                      \
    float mm_ = ((h_) == 1) ? 1.f : 0.f;                                      \
    cnt += mm_;                                                               \
    float w0_ = (p0_) * mm_, w1_ = (p1_) * mm_, w2_ = (p2_) * mm_,            \
          w3_ = (p3_) * mm_;                                                  \
    s0_0 += w0_; s0_1 += w1_; s0_2 += w2_; s0_3 += w3_;                       \
    float t_;                                                                 \
    t_ = w0_ * (e0_); u00 += t_; q00 = fmaf(t_, (e0_), q00);                  \
    t_ = w0_ * (e1_); u01 += t_; q01 = fmaf(t_, (e1_), q01);                  \
    t_ = w0_ * (e2_); u02 += t_; q02 = fmaf(t_, (e2_), q02);                  \
    t_ = w1_ * (e0_); u10 += t_; q10 = fmaf(t_, (e0_), q10);                  \
    t_ = w1_ * (e1_); u11 += t_; q11 = fmaf(t_, (e1_), q11);                  \
    t_ = w1_ * (e2_); u12 += t_; q12 = fmaf(t_, (e2_), q12);                  \
    t_ = w2_ * (e0_); u20 += t_; q20 = fmaf(t_, (e0_), q20);                  \
    t_ = w2_ * (e1_); u21 += t_; q21 = fmaf(t_, (e1_), q21);                  \
    t_ = w2_ * (e2_); u22 += t_; q22 = fmaf(t_, (e2_), q22);                  \
    t_ = w3_ * (e0_); u30 += t_; q30 = fmaf(t_, (e0_), q30);                  \
    t_ = w3_ * (e1_); u31 += t_; q31 = fmaf(t_, (e1_), q31);                  \
    t_ = w3_ * (e2_); u32 += t_; q32 = fmaf(t_, (e2_), q32);                  \
} while (0)

#define RED(i_, var_) { float r_ = waveReduce64(var_); if (lane == 0) sh[wav][i_] = r_; }

__global__ __launch_bounds__(256) void pass1_moments(
        const float* __restrict__ predictions,
        const float* __restrict__ inputs,
        const int*   __restrict__ heart,
        double*      __restrict__ ws) {
    const int b = blockIdx.y;
    const float4* P1 = reinterpret_cast<const float4*>(predictions + (size_t)b * 5 * XY + 1 * XY);
    const float4* P2 = reinterpret_cast<const float4*>(predictions + (size_t)b * 5 * XY + 2 * XY);
    const float4* P3 = reinterpret_cast<const float4*>(predictions + (size_t)b * 5 * XY + 3 * XY);
    const float4* P4 = reinterpret_cast<const float4*>(predictions + (size_t)b * 5 * XY + 4 * XY);
    const float4* I0 = reinterpret_cast<const float4*>(inputs + (size_t)b * 3 * XY + 0 * XY);
    const float4* I1 = reinterpret_cast<const float4*>(inputs + (size_t)b * 3 * XY + 1 * XY);
    const float4* I2 = reinterpret_cast<const float4*>(inputs + (size_t)b * 3 * XY + 2 * XY);
    const int4*   H  = reinterpret_cast<const int4*>(heart + (size_t)b * XY);

    float cnt = 0.f;
    float s0_0 = 0.f, s0_1 = 0.f, s0_2 = 0.f, s0_3 = 0.f;
    float u00 = 0.f, u01 = 0.f, u02 = 0.f, u10 = 0.f, u11 = 0.f, u12 = 0.f;
    float u20 = 0.f, u21 = 0.f, u22 = 0.f, u30 = 0.f, u31 = 0.f, u32 = 0.f;
    float q00 = 0.f, q01 = 0.f, q02 = 0.f, q10 = 0.f, q11 = 0.f, q12 = 0.f;
    float q20 = 0.f, q21 = 0.f, q22 = 0.f, q30 = 0.f, q31 = 0.f, q32 = 0.f;

    const int tid0   = blockIdx.x * blockDim.x + threadIdx.x;
    const int stride = gridDim.x * blockDim.x;

    for (int v = tid0; v < NV; v += stride) {
        int4   h  = H[v];
        float4 f0 = I0[v], f1 = I1[v], f2 = I2[v];
        float4 g0 = P1[v], g1 = P2[v], g2 = P3[v], g3 = P4[v];
        PIX1(h.x, f0.x, f1.x, f2.x, g0.x, g1.x, g2.x, g3.x);
        PIX1(h.y, f0.y, f1.y, f2.y, g0.y, g1.y, g2.y, g3.y);
        PIX1(h.z, f0.z, f1.z, f2.z, g0.z, g1.z, g2.z, g3.z);
        PIX1(h.w, f0.w, f1.w, f2.w, g0.w, g1.w, g2.w, g3.w);
    }

    __shared__ float sh[4][29];
    const int lane = threadIdx.x & 63;
    const int wav  = threadIdx.x >> 6;
    RED(0, cnt);
    RED(1, s0_0); RED(2, s0_1); RED(3, s0_2); RED(4, s0_3);
    RED(5, u00); RED(6, u01); RED(7, u02);
    RED(8, u10); RED(9, u11); RED(10, u12);
    RED(11, u20); RED(12, u21); RED(13, u22);
    RED(14, u30); RED(15, u31); RED(16, u32);
    RED(17, q00); RED(18, q01); RED(19, q02);
    RED(20, q10); RED(21, q11); RED(22, q12);
    RED(23, q20); RED(24, q21); RED(25, q22);
    RED(26, q30); RED(27, q31); RED(28, q32);
    __syncthreads();
    if (threadIdx.x < 29) {
        float v = sh[0][threadIdx.x] + sh[1][threadIdx.x] + sh[2][threadIdx.x] + sh[3][threadIdx.x];
        atomicAdd(&ws[(size_t)b * WS_STRIDE + threadIdx.x], (double)v);
    }
}

// Per-component parameter reconstruction (block-uniform, f64 for the ~4x
// cancellation in S2 - 2 mu S1 + mu^2 S0).
#define PARAMK(K_, mu0_, mu1_, mu2_, h0_, h1_, h2_, C_) {                     \
    double S0_ = w[1 + (K_)];                                                 \
    double den_ = S0_ + 1e-10;                                                \
    double Cd_ = 1.0;                                                         \
    double S1_, S2_, muv_, var_;                                              \
    S1_ = w[5 + (K_)*3 + 0]; S2_ = w[17 + (K_)*3 + 0];                        \
    muv_ = S1_ / den_;                                                        \
    var_ = (S2_ - 2.0 * muv_ * S1_ + muv_ * muv_ * S0_) / den_ + 1e-10;       \
    mu0_ = (float)muv_; h0_ = (float)(0.5 / var_);                            \
    Cd_ *= 1.0 / sqrt(6.283185307179586 * var_);                              \
    S1_ = w[5 + (K_)*3 + 1]; S2_ = w[17 + (K_)*3 + 1];                        \
    muv_ = S1_ / den_;                                                        \
    var_ = (S2_ - 2.0 * muv_ * S1_ + muv_ * muv_ * S0_) / den_ + 1e-10;       \
    mu1_ = (float)muv_; h1_ = (float)(0.5 / var_);                            \
    Cd_ *= 1.0 / sqrt(6.283185307179586 * var_);                              \
    S1_ = w[5 + (K_)*3 + 2]; S2_ = w[17 + (K_)*3 + 2];                        \
    muv_ = S1_ / den_;                                                        \
    var_ = (S2_ - 2.0 * muv_ * S1_ + muv_ * muv_ * S0_) / den_ + 1e-10;       \
    mu2_ = (float)muv_; h2_ = (float)(0.5 / var_);                            \
    Cd_ *= 1.0 / sqrt(6.283185307179586 * var_);                              \
    C_ = (float)Cd_;                                                          \
}

#define PIX2(h_, e0_, e1_, e2_, p0_, p1_, p2_, p3_) do {                      \
    float m_ = ((h_) == 1) ? 1.f : 0.f;                                       \
    float d0_, d1_, d2_, ex_, pc_;                                            \
    float mix_;                                                               \
    d0_ = (e0_) - mu00; d1_ = (e1_) - mu01; d2_ = (e2_) - mu02;               \
    ex_ = fmaf(d0_ * d0_, hv00, fmaf(d1_ * d1_, hv01, d2_ * d2_ * hv02));     \
    pc_ = (p0_) * (p0_) * (p0_);                                              \
    mix_ = C0 * pc_ * __expf(-ex_);                                           \
    d0_ = (e0_) - mu10; d1_ = (e1_) - mu11; d2_ = (e2_) - mu12;               \
    ex_ = fmaf(d0_ * d0_, hv10, fmaf(d1_ * d1_, hv11, d2_ * d2_ * hv12));     \
    pc_ = (p1_) * (p1_) * (p1_);                                              \
    mix_ = fmaf(C1 * pc_, __expf(-ex_), mix_);                                \
    d0_ = (e0_) - mu20; d1_ = (e1_) - mu21; d2_ = (e2_) - mu22;               \
    ex_ = fmaf(d0_ * d0_, hv20, fmaf(d1_ * d1_, hv21, d2_ * d2_ * hv22));     \
    pc_ = (p2_) * (p2_) * (p2_);                                              \
    mix_ = fmaf(C2 * pc_, __expf(-ex_), mix_);                                \
    d0_ = (e0_) - mu30; d1_ = (e1_) - mu31; d2_ = (e2_) - mu32;               \
    ex_ = fmaf(d0_ * d0_, hv30, fmaf(d1_ * d1_, hv31, d2_ * d2_ * hv32));     \
    pc_ = (p3_) * (p3_) * (p3_);                                              \
    mix_ = fmaf(C3 * pc_, __expf(-ex_), mix_);                                \
    lacc += m_ * __logf(mix_ + 1e-10f);                                       \
} while (0)

__global__ __launch_bounds__(256) void pass2_loglik(
        const float* __restrict__ predictions,
        const float* __restrict__ inputs,
        const int*   __restrict__ heart,
        double*      __restrict__ ws) {
    const int b = blockIdx.y;
    const double* w = ws + (size_t)b * WS_STRIDE;

    float mu00, mu01, mu02, mu10, mu11, mu12, mu20, mu21, mu22, mu30, mu31, mu32;
    float hv00, hv01, hv02, hv10, hv11, hv12, hv20, hv21, hv22, hv30, hv31, hv32;
    float C0, C1, C2, C3;
    PARAMK(0, mu00, mu01, mu02, hv00, hv01, hv02, C0);
    PARAMK(1, mu10, mu11, mu12, hv10, hv11, hv12, C1);
    PARAMK(2, mu20, mu21, mu22, hv20, hv21, hv22, C2);
    PARAMK(3, mu30, mu31, mu32, hv30, hv31, hv32, C3);

    const float4* P1 = reinterpret_cast<const float4*>(predictions + (size_t)b * 5 * XY + 1 * XY);
    const float4* P2 = reinterpret_cast<const float4*>(predictions + (size_t)b * 5 * XY + 2 * XY);
    const float4* P3 = reinterpret_cast<const float4*>(predictions + (size_t)b * 5 * XY + 3 * XY);
    const float4* P4 = reinterpret_cast<const float4*>(predictions + (size_t)b * 5 * XY + 4 * XY);
    const float4* I0 = reinterpret_cast<const float4*>(inputs + (size_t)b * 3 * XY + 0 * XY);
    const float4* I1 = reinterpret_cast<const float4*>(inputs + (size_t)b * 3 * XY + 1 * XY);
    const float4* I2 = reinterpret_cast<const float4*>(inputs + (size_t)b * 3 * XY + 2 * XY);
    const int4*   H  = reinterpret_cast<const int4*>(heart + (size_t)b * XY);

    float lacc = 0.f;
    const int tid0   = blockIdx.x * blockDim.x + threadIdx.x;
    const int stride = gridDim.x * blockDim.x;

    for (int v = tid0; v < NV; v += stride) {
        int4   h  = H[v];
        float4 f0 = I0[v], f1 = I1[v], f2 = I2[v];
        float4 g0 = P1[v], g1 = P2[v], g2 = P3[v], g3 = P4[v];
        PIX2(h.x, f0.x, f1.x, f2.x, g0.x, g1.x, g2.x, g3.x);
        PIX2(h.y, f0.y, f1.y, f2.y, g0.y, g1.y, g2.y, g3.y);
        PIX2(h.z, f0.z, f1.z, f2.z, g0.z, g1.z, g2.z, g3.z);
        PIX2(h.w, f0.w, f1.w, f2.w, g0.w, g1.w, g2.w, g3.w);
    }

    __shared__ float sh[4];
    const int lane = threadIdx.x & 63;
    const int wav  = threadIdx.x >> 6;
    float v = waveReduce64(lacc);
    if (lane == 0) sh[wav] = v;
    __syncthreads();
    if (threadIdx.x == 0) {
        float t = sh[0] + sh[1] + sh[2] + sh[3];
        atomicAdd(&ws[(size_t)b * WS_STRIDE + 29], (double)t);
    }
}

__global__ void finalize_kernel(const double* __restrict__ ws, float* __restrict__ out) {
    const int lane = threadIdx.x;
    double v = 0.0;
    if (lane < NB) {
        double cntv = ws[(size_t)lane * WS_STRIDE + 0];
        double ll   = ws[(size_t)lane * WS_STRIDE + 29];
        v = -ll / cntv;
    }
#pragma unroll
    for (int off = 8; off > 0; off >>= 1) v += __shfl_down(v, off, 64);
    if (lane == 0) out[0] = (float)(v / (double)NB);
}

extern "C" void kernel_launch(void* const* d_in, const int* in_sizes, int n_in,
                              void* d_out, int out_size, void* d_ws, size_t ws_size,
                              hipStream_t stream) {
    const float* predictions = (const float*)d_in[0];
    const float* inputs      = (const float*)d_in[1];
    const int*   heart       = (const int*)d_in[2];
    float*  out = (float*)d_out;
    double* ws  = (double*)d_ws;

    // zero the accumulator workspace (harness poisons it with 0xAA)
    hipMemsetAsync(d_ws, 0, (size_t)NB * WS_STRIDE * sizeof(double), stream);

    pass1_moments<<<dim3(64, NB), 256, 0, stream>>>(predictions, inputs, heart, ws);
    pass2_loglik <<<dim3(64, NB), 256, 0, stream>>>(predictions, inputs, heart, ws);
    finalize_kernel<<<1, 64, 0, stream>>>(ws, out);
}